// Round 6
// baseline (282.826 us; speedup 1.0000x reference)
//
#include <hip/hip_runtime.h>
#include <hip/hip_bf16.h>

typedef float f32x4 __attribute__((ext_vector_type(4)));
typedef short s16x8 __attribute__((ext_vector_type(8)));
typedef unsigned long long ull;

#define NROWS 8192
#define MCOLS 8192
#define DIM   128
#define BI    32
#define NTILE 256   // MCOLS / 32

// ---- prep: per-row norm + bf16 convert for BOTH xi (scaled by beta) and xj ----
__global__ void prep_scale_both(const float* __restrict__ xi,
                                const float* __restrict__ xj,
                                const float* __restrict__ beta,
                                __hip_bfloat16* __restrict__ Qbf,
                                __hip_bfloat16* __restrict__ Kbf) {
    int gr = blockIdx.x * 4 + (threadIdx.x >> 6);
    int l = threadIdx.x & 63;
    const float* src;
    __hip_bfloat16* dst;
    int row;
    if (gr < NROWS) { row = gr;          src = xi; dst = Qbf; }
    else            { row = gr - NROWS;  src = xj; dst = Kbf; }
    const float* xr = src + (size_t)row * DIM;
    float x0 = xr[l], x1 = xr[l + 64];
    float ss = x0 * x0 + x1 * x1;
#pragma unroll
    for (int off = 32; off >= 1; off >>= 1) ss += __shfl_xor(ss, off);
    float s = 1.0f / sqrtf(ss);
    if (gr < NROWS) s *= beta[0];
    __hip_bfloat16* o = dst + (size_t)row * DIM;
    o[l]      = __float2bfloat16(x0 * s);
    o[l + 64] = __float2bfloat16(x1 * s);
}

// ---- prep: transpose xj -> Vt[d][j] bf16 (raw values) ----
__global__ void prep_vt(const float* __restrict__ xj, __hip_bfloat16* __restrict__ vt) {
    __shared__ float tile[64][65];
    int j0 = blockIdx.x * 64;
    int d0 = blockIdx.y * 64;
    int t = threadIdx.x; // 256
#pragma unroll
    for (int c = 0; c < 16; ++c) {
        int idx = t + 256 * c;
        int jr = idx >> 6, dc = idx & 63;
        tile[jr][dc] = xj[(size_t)(j0 + jr) * DIM + d0 + dc];
    }
    __syncthreads();
#pragma unroll
    for (int c = 0; c < 16; ++c) {
        int idx = t + 256 * c;
        int dr = idx >> 6, jc = idx & 63;
        vt[(size_t)(d0 + dr) * MCOLS + j0 + jc] = __float2bfloat16(tile[jc][dr]);
    }
}

// ---- flash attention, two-phase:
//      phase 1: block ballot-packs its 32x8192 adj slab -> 32KB LDS bits.
//               (only HBM loads in the wave FIFO -> streams at HBM roofline)
//      phase 2: MFMA loop with mask from LDS, K/V from L2. NO HBM in loop ->
//               homogeneous L2 latency, counted vmcnt waits work, 4 waves/SIMD.
//      no max-tracking softmax (|score| <= beta < 1): p = adj ? exp(s) : 0 ----
__global__ __launch_bounds__(1024) void flash6(const __hip_bfloat16* __restrict__ Qbf,
                                               const __hip_bfloat16* __restrict__ Kbf,
                                               const __hip_bfloat16* __restrict__ Vt,
                                               const int* __restrict__ adj,
                                               float* __restrict__ out) {
    __shared__ char smem[66048];
    unsigned int*   bits  = (unsigned int*)smem;       // [32][256] uint32 = 32 KiB
    ull*            bits64 = (ull*)smem;               // alias for packing writes
    __hip_bfloat16* Plds  = (__hip_bfloat16*)(smem + 32768); // [16 waves][16][40] = 20 KiB
    float*          Opart = (float*)smem;              // epilogue reuse: [8][16][128] = 64 KiB
    float*          Lpart = (float*)(smem + 65536);    // epilogue: [8][16]

    const int tid  = threadIdx.x;
    const int w    = tid >> 6;
    const int lane = tid & 63;
    const int g    = lane >> 4;
    const int ln   = lane & 15;
    const int rg   = w >> 3;   // 0..1 row group (16 rows)
    const int wj   = w & 7;    // 0..7 j slice (32 tiles each)
    const int i0   = blockIdx.x * BI;
    const int ri0  = i0 + rg * 16;

    // ---- phase 1: pack adj slab to LDS bits ----
    // unit u = w*256 + k: row r = u>>7 (0..31), colgroup cg = u&127 (64 cols)
    {
        const int* abase = adj + (size_t)i0 * MCOLS + lane;
        for (int k = 0; k < 256; k += 8) {
            int a[8];
#pragma unroll
            for (int u = 0; u < 8; ++u) {
                int unit = w * 256 + k + u;
                a[u] = abase[(size_t)(unit >> 7) * MCOLS + (unit & 127) * 64];
            }
#pragma unroll
            for (int u = 0; u < 8; ++u) {
                ull b = __ballot(a[u] != 0);
                int unit = w * 256 + k + u;
                if (lane == 0) bits64[(unit >> 7) * 128 + (unit & 127)] = b;
            }
        }
    }
    __syncthreads();

    // ---- phase 2: MFMA loop ----
    s16x8 qf[4];
#pragma unroll
    for (int kt = 0; kt < 4; ++kt)
        qf[kt] = *(const s16x8*)(Qbf + (size_t)(ri0 + ln) * DIM + kt * 32 + g * 8);

    f32x4 zero = {0.f, 0.f, 0.f, 0.f};
    f32x4 acc[8];
#pragma unroll
    for (int dt = 0; dt < 8; ++dt) acc[dt] = zero;
    float lr[4] = {0.f, 0.f, 0.f, 0.f};

    __hip_bfloat16* pme = Plds + w * 640; // [16][40] bf16 per wave
    const unsigned int* mrow = bits + (rg * 16 + g * 4) * NTILE;

    for (int tt = 0; tt < 32; ++tt) {
        const int t  = wj * 32 + tt;
        const int jt = t * 32;

        // mask words (LDS, broadcast within 16-lane group)
        unsigned int wd[4];
#pragma unroll
        for (int r = 0; r < 4; ++r) wd[r] = mrow[r * NTILE + t];

        // K fragments (L2)
        s16x8 kf[2][4];
#pragma unroll
        for (int jt2 = 0; jt2 < 2; ++jt2)
#pragma unroll
            for (int kt = 0; kt < 4; ++kt)
                kf[jt2][kt] = *(const s16x8*)(Kbf + (size_t)(jt + jt2 * 16 + ln) * DIM + kt * 32 + g * 8);

        // S = Q K^T
        f32x4 s0 = zero, s1 = zero;
#pragma unroll
        for (int kt = 0; kt < 4; ++kt) {
            s0 = __builtin_amdgcn_mfma_f32_16x16x32_bf16(qf[kt], kf[0][kt], s0, 0, 0, 0);
            s1 = __builtin_amdgcn_mfma_f32_16x16x32_bf16(qf[kt], kf[1][kt], s1, 0, 0, 0);
        }

        // p = adj ? exp(s) : 0
#pragma unroll
        for (int r = 0; r < 4; ++r) {
            float p0 = ((wd[r] >> ln) & 1u)        ? __expf(s0[r]) : 0.f;
            float p1 = ((wd[r] >> (16 + ln)) & 1u) ? __expf(s1[r]) : 0.f;
            lr[r] += p0 + p1;
            pme[(g * 4 + r) * 40 + ln]      = __float2bfloat16(p0);
            pme[(g * 4 + r) * 40 + 16 + ln] = __float2bfloat16(p1);
        }

        // PV (same-wave LDS RAW; V fragments from L2)
        s16x8 pf = *(const s16x8*)(pme + ln * 40 + g * 8);
#pragma unroll
        for (int dt = 0; dt < 8; ++dt) {
            s16x8 vfrag = *(const s16x8*)(Vt + (size_t)(dt * 16 + ln) * MCOLS + jt + g * 8);
            acc[dt] = __builtin_amdgcn_mfma_f32_16x16x32_bf16(pf, vfrag, acc[dt], 0, 0, 0);
        }
    }

    // row sums (within 16-lane group)
#pragma unroll
    for (int r = 0; r < 4; ++r) {
        lr[r] += __shfl_xor(lr[r], 1);
        lr[r] += __shfl_xor(lr[r], 2);
        lr[r] += __shfl_xor(lr[r], 4);
        lr[r] += __shfl_xor(lr[r], 8);
    }

    // ---- merge 8 j-slice partials per row group (plain sums) ----
#pragma unroll
    for (int rgo = 0; rgo < 2; ++rgo) {
        __syncthreads();
        if (rg == rgo) {
#pragma unroll
            for (int dt = 0; dt < 8; ++dt)
#pragma unroll
                for (int r = 0; r < 4; ++r)
                    Opart[(wj * 16 + g * 4 + r) * 128 + dt * 16 + ln] = acc[dt][r];
            if (ln == 0) {
#pragma unroll
                for (int r = 0; r < 4; ++r) Lpart[wj * 16 + g * 4 + r] = lr[r];
            }
        }
        __syncthreads();
        const int row = tid >> 6;          // 0..15
        const int c2  = (tid & 63) * 2;    // 0..126
        float L = 0.f;
#pragma unroll
        for (int p = 0; p < 8; ++p) L += Lpart[p * 16 + row];
        float o0 = 0.f, o1 = 0.f;
#pragma unroll
        for (int p = 0; p < 8; ++p) {
            const float* op = Opart + (p * 16 + row) * 128 + c2;
            o0 += op[0];
            o1 += op[1];
        }
        float inv = 1.0f / fmaxf(L, 1e-37f);
        float2 ov = {o0 * inv, o1 * inv};
        *(float2*)(out + (size_t)(i0 + rgo * 16 + row) * DIM + c2) = ov;
    }
}

extern "C" void kernel_launch(void* const* d_in, const int* in_sizes, int n_in,
                              void* d_out, int out_size, void* d_ws, size_t ws_size,
                              hipStream_t stream) {
    const float* xi   = (const float*)d_in[0];
    const float* xj   = (const float*)d_in[1];
    const int*   adj  = (const int*)d_in[2];
    const float* beta = (const float*)d_in[3];
    float* out = (float*)d_out;

    char* ws = (char*)d_ws;
    __hip_bfloat16* Qbf = (__hip_bfloat16*)ws;                                   // 2 MiB
    __hip_bfloat16* Kbf = (__hip_bfloat16*)(ws + (size_t)NROWS * DIM * 2);       // 2 MiB
    __hip_bfloat16* Vt  = (__hip_bfloat16*)(ws + 2 * (size_t)NROWS * DIM * 2);   // 2 MiB

    hipLaunchKernelGGL(prep_scale_both, dim3(4096), dim3(256), 0, stream, xi, xj, beta, Qbf, Kbf);
    hipLaunchKernelGGL(prep_vt, dim3(128, 2), dim3(256), 0, stream, xj, Vt);
    hipLaunchKernelGGL(flash6, dim3(NROWS / BI), dim3(1024), 0, stream, Qbf, Kbf, Vt, adj, out);
}